// Round 5
// baseline (589.856 us; speedup 1.0000x reference)
//
#include <hip/hip_runtime.h>

typedef unsigned short u16;
typedef __bf16 bf16x8 __attribute__((ext_vector_type(8)));
typedef float f32x4 __attribute__((ext_vector_type(4)));
typedef u16 u16x8 __attribute__((ext_vector_type(8)));

static constexpr int kNRoi = 2000;
static constexpr int kMPad = 2048;
static constexpr int kKin  = 12544;
static constexpr int kHid  = 1024;
static constexpr int kNOutPad = 512;
static constexpr int kNC = 81;
static constexpr int kND = 324;

// Session ledger:
// R1: LDS XOR-swizzle verified (bank conflicts 6.4M->0) but null on time.
// R2: 256^2 w/ vmcnt(0)-per-iter: MfmaUtil 20%; GEMM2/3 atomic storm regressed.
// R3: crashed (workspace >91.6MB proven limit).
// R4: AF32-fused GEMM1 regressed (thin latency cover). KEY FINDING: per-kernel
//     estimates sum to ~240us vs 441 measured across R0/R2/R4 -- ~17-20us of
//     fixed overhead PER LAUNCH. 9 launches = ~170us of pure overhead.
// R5 (this): ONE persistent kernel, 256 blocks x 512 thr (1 block/CU via
//     128KiB LDS => all co-resident), custom device-scope grid barrier
//     (self-resetting, graph-replay-safe). GEMM1 = 256^2/BK64/8-wave with
//     counted vmcnt(8) on iteration-old loads; atomics into X (hidden under
//     long NT per R0/R2). GEMM2/3 = 256x128 direct-store partials (no atomics).

__device__ unsigned g_cnt = 0;   // arrival counter (self-resets each barrier)
__device__ unsigned g_gen = 0;   // generation (monotonic, wraps harmlessly)

__device__ __forceinline__ void gsync() {
  __syncthreads();
  if (threadIdx.x == 0) {
    __threadfence();                                   // release (wbl2)
    unsigned my = atomicAdd(&g_gen, 0u);
    unsigned n = atomicAdd(&g_cnt, 1u) + 1;
    if (n == 256u) {
      atomicExch(&g_cnt, 0u);
      __threadfence();
      atomicAdd(&g_gen, 1u);
    } else {
      while (atomicAdd(&g_gen, 0u) == my) {}
    }
    __threadfence();                                   // acquire (inv)
  }
  __syncthreads();
}

__device__ __forceinline__ u16 f2bf(float f) {
  union { float f; unsigned u; } v; v.f = f;
  unsigned r = v.u + 0x7fffu + ((v.u >> 16) & 1u);     // RNE, finite inputs only
  return (u16)(r >> 16);
}

#define GLDS(p, d) __builtin_amdgcn_global_load_lds( \
    (const __attribute__((address_space(1))) void*)(p), \
    (__attribute__((address_space(3))) void*)(d), 16, 0, 0)

// ---- 64x64 f32->bf16 transpose tile, 512 threads, t = 64*72 u16 ------------
__device__ __forceinline__ void tr64(const float* __restrict__ src,
                                     u16* __restrict__ dst, int R,
                                     int cb, int rb, u16* t, int tid) {
  const int rl = tid >> 3, cl = (tid & 7) * 8;
  f32x4 v0 = *(const f32x4*)(src + (long)(rb + rl) * 1024 + cb + cl);
  f32x4 v1 = *(const f32x4*)(src + (long)(rb + rl) * 1024 + cb + cl + 4);
#pragma unroll
  for (int j = 0; j < 4; ++j) {
    t[(cl + j) * 72 + rl] = f2bf(v0[j]);
    t[(cl + 4 + j) * 72 + rl] = f2bf(v1[j]);
  }
  __syncthreads();
  *(u16x8*)(dst + (long)(cb + rl) * R + rb + cl) = *(const u16x8*)&t[rl * 72 + cl];
  __syncthreads();
}

// ---- 32x32 bounds-checked transpose tile, 512 threads, t = 32*33 u16 -------
__device__ __forceinline__ void tr32(const float* __restrict__ src,
                                     u16* __restrict__ dst, int srcC,
                                     int cb, int rb, u16* t, int tid) {
  const int tx = tid & 31, ty = tid >> 5;              // ty 0..15
#pragma unroll
  for (int j = 0; j < 2; ++j) {
    int r = rb + ty + j * 16, c = cb + tx;
    if (c < srcC) t[(ty + j * 16) * 33 + tx] = f2bf(src[(long)r * srcC + c]);
  }
  __syncthreads();
#pragma unroll
  for (int j = 0; j < 2; ++j) {
    int c = cb + ty + j * 16, r = rb + tx;
    if (c < srcC) dst[(long)c * 1024 + r] = t[tx * 33 + ty + j * 16];
  }
  __syncthreads();
}

// ---- BN(train)+ReLU+bf16, 16 elems/thread ----------------------------------
__device__ __forceinline__ void bn_phase(const float* __restrict__ X,
    const float* __restrict__ Sv, const float* __restrict__ SSv,
    const float* __restrict__ gamma, const float* __restrict__ beta,
    u16* __restrict__ H, int g) {
  constexpr float invN = 1.f / (float)kNRoi;
#pragma unroll
  for (int h2 = 0; h2 < 2; ++h2) {
    long i = (long)g * 16 + h2 * 8;
    int c = (int)(i & (kHid - 1));
    f32x4 x0 = *(const f32x4*)(X + i);
    f32x4 x1 = *(const f32x4*)(X + i + 4);
    f32x4 s0 = *(const f32x4*)(Sv + c),    s1 = *(const f32x4*)(Sv + c + 4);
    f32x4 q0 = *(const f32x4*)(SSv + c),   q1 = *(const f32x4*)(SSv + c + 4);
    f32x4 g0 = *(const f32x4*)(gamma + c), g1 = *(const f32x4*)(gamma + c + 4);
    f32x4 b0 = *(const f32x4*)(beta + c),  b1 = *(const f32x4*)(beta + c + 4);
    u16x8 h;
#pragma unroll
    for (int j = 0; j < 4; ++j) {
      float mu = s0[j] * invN;
      float var = q0[j] * invN - mu * mu;
      float sc = g0[j] * rsqrtf(var + 1e-3f);
      h[j] = f2bf(fmaxf(0.f, sc * x0[j] + (b0[j] - mu * sc)));
      mu = s1[j] * invN;
      var = q1[j] * invN - mu * mu;
      sc = g1[j] * rsqrtf(var + 1e-3f);
      h[4 + j] = f2bf(fmaxf(0.f, sc * x1[j] + (b1[j] - mu * sc)));
    }
    *(u16x8*)(H + i) = h;
  }
}

// ---- 256x128/BK64/8-wave GEMM, counted vmcnt, direct-store -----------------
// Wave tile 64x64 (2M x 2N wave grid). LDS XOR-swizzle both sides (rule 21).
__device__ __forceinline__ void gemm_bn128(
    const u16* __restrict__ Ab, const u16* __restrict__ Btb,
    float* __restrict__ Cw, int bxm, int byn, int kb, int NT, int N,
    u16 (*Asb)[16384], u16 (*Bsb)[16384], int tid) {
  const int lane = tid & 63, w = tid >> 6;
  const int wm = (w >> 1) * 64, wn = (w & 1) * 64;
  const int rS = tid >> 3;
  const int sg = (tid & 7) ^ (rS & 7);
  const u16* aq[4]; const u16* bq[2];
#pragma unroll
  for (int j = 0; j < 4; ++j)
    aq[j] = Ab + (long)(bxm * 256 + rS + j * 64) * 1024 + kb + sg * 8;
#pragma unroll
  for (int j = 0; j < 2; ++j)
    bq[j] = Btb + (long)(byn * 128 + rS + j * 64) * 1024 + kb + sg * 8;

#define STAGE2(b) do { _Pragma("unroll") for (int j_ = 0; j_ < 4; ++j_) { \
      GLDS(aq[j_], &Asb[b][w * 512 + j_ * 4096]); aq[j_] += 64; } \
    _Pragma("unroll") for (int j_ = 0; j_ < 2; ++j_) { \
      GLDS(bq[j_], &Bsb[b][w * 512 + j_ * 4096]); bq[j_] += 64; } } while (0)

  const int fr = lane & 15, q = lane >> 4;
  const int g0 = (q ^ (fr & 7)) * 8, g1 = ((4 + q) ^ (fr & 7)) * 8;
  f32x4 acc[4][4] = {};

  STAGE2(0);
  int cur = 0;
  for (int t = 0; t < NT; ++t) {
    const int nb = cur ^ 1;
    const bool more = (t + 1 < NT);
    __builtin_amdgcn_s_barrier();                     // buf[nb] free
    if (more) {
      STAGE2(nb);
      asm volatile("s_waitcnt vmcnt(6)" ::: "memory"); // tile t landed
    } else {
      asm volatile("s_waitcnt vmcnt(0)" ::: "memory");
    }
    __builtin_amdgcn_s_barrier();                     // tile t visible
    __builtin_amdgcn_sched_barrier(0);
    const u16* as_ = Asb[cur];
    const u16* bs_ = Bsb[cur];
    bf16x8 a0[4], b0[4], a1[4], b1[4];
#pragma unroll
    for (int i = 0; i < 4; ++i) a0[i] = *(const bf16x8*)(as_ + (wm + i * 16 + fr) * 64 + g0);
#pragma unroll
    for (int i = 0; i < 4; ++i) b0[i] = *(const bf16x8*)(bs_ + (wn + i * 16 + fr) * 64 + g0);
    __builtin_amdgcn_s_setprio(1);
#pragma unroll
    for (int mi = 0; mi < 4; ++mi)
#pragma unroll
      for (int ni = 0; ni < 4; ++ni)
        acc[mi][ni] = __builtin_amdgcn_mfma_f32_16x16x32_bf16(a0[mi], b0[ni], acc[mi][ni], 0, 0, 0);
    __builtin_amdgcn_s_setprio(0);
#pragma unroll
    for (int i = 0; i < 4; ++i) a1[i] = *(const bf16x8*)(as_ + (wm + i * 16 + fr) * 64 + g1);
#pragma unroll
    for (int i = 0; i < 4; ++i) b1[i] = *(const bf16x8*)(bs_ + (wn + i * 16 + fr) * 64 + g1);
    __builtin_amdgcn_s_setprio(1);
#pragma unroll
    for (int mi = 0; mi < 4; ++mi)
#pragma unroll
      for (int ni = 0; ni < 4; ++ni)
        acc[mi][ni] = __builtin_amdgcn_mfma_f32_16x16x32_bf16(a1[mi], b1[ni], acc[mi][ni], 0, 0, 0);
    __builtin_amdgcn_s_setprio(0);
    cur = nb;
  }
#undef STAGE2
  const int row0 = bxm * 256 + wm + q * 4;
  const int col0 = byn * 128 + wn + fr;
#pragma unroll
  for (int mi = 0; mi < 4; ++mi)
#pragma unroll
    for (int ni = 0; ni < 4; ++ni)
#pragma unroll
      for (int e = 0; e < 4; ++e)
        Cw[(long)(row0 + mi * 16 + e) * N + col0 + ni * 16] = acc[mi][ni][e];
}

// ---- the whole net in one launch -------------------------------------------
__global__ __launch_bounds__(512, 2) void mega(
    const float* __restrict__ pooled, const float* __restrict__ w1,
    const float* __restrict__ w2, const float* __restrict__ wl,
    const float* __restrict__ wd, const float* __restrict__ gamma1,
    const float* __restrict__ beta1, const float* __restrict__ gamma2,
    const float* __restrict__ beta2, const float* __restrict__ blg,
    const float* __restrict__ bdl, u16* __restrict__ A1,
    u16* __restrict__ W1T, u16* __restrict__ W2T, u16* __restrict__ WHT,
    float* __restrict__ X, float* __restrict__ S, u16* __restrict__ H,
    float* __restrict__ Pz, float* __restrict__ out) {
  __shared__ u16 As[2][16384];
  __shared__ u16 Bs[2][16384];
  const int tid = threadIdx.x;
  const int bl = blockIdx.x;
  const int g = bl * 512 + tid;
  const int lane = tid & 63;
  const int w = tid >> 6;
  float* S1 = S; float* SS1 = S + 1024; float* S2 = S + 2048; float* SS2 = S + 3072;

  // ============ phase 0: prep (A-convert, transposes, zeros) ============
  for (long i = (long)g * 8; i < 25088000L; i += 131072L * 8) {
    f32x4 a = *(const f32x4*)(pooled + i);
    f32x4 b = *(const f32x4*)(pooled + i + 4);
    u16x8 h;
#pragma unroll
    for (int j = 0; j < 4; ++j) { h[j] = f2bf(a[j]); h[4 + j] = f2bf(b[j]); }
    *(u16x8*)(A1 + i) = h;
  }
  {
    u16* t = As[0];
    for (int it = 0; it < 13; ++it) {                 // W1T: 3136 tiles
      int tt = bl + it * 256;
      if (tt < 3136) tr64(w1, W1T, kKin, (tt & 15) * 64, (tt >> 4) * 64, t, tid);
    }
    tr64(w2, W2T, kHid, (bl & 15) * 64, (bl >> 4) * 64, t, tid);  // 256 tiles
    for (int it = 0; it < 2; ++it) {                  // WHT: 96 + 352 tiles
      int tt = bl + it * 256;
      if (tt < 96) tr32(wl, WHT, kNC, (tt % 3) * 32, (tt / 3) * 32, t, tid);
      else if (tt < 448) {
        int u = tt - 96;
        tr32(wd, WHT + kNC * kHid, kND, (u % 11) * 32, (u / 11) * 32, t, tid);
      }
    }
  }
  if (g < 13696) *(u16x8*)(WHT + 405 * kHid + (long)g * 8) = (u16x8){};  // pad
  if (g < 1024)  *(f32x4*)(S + g * 4) = (f32x4){};
#pragma unroll
  for (int k = 0; k < 4; ++k)                          // zero X (GEMM1 target)
    *(f32x4*)(X + ((long)(g + k * 131072)) * 4) = (f32x4){};
  gsync();

  // ============ phase 1: GEMM1 256^2 split-K8, atomics into X ============
  {
    const int z  = bl & 7;
    const int bx = (bl >> 3) & 7;
    const int by = bl >> 6;
    const int NT = 24 + (z < 4 ? 1 : 0);
    const long kb = (long)(z * 24 + (z < 4 ? z : 4)) * 64;
    const int wm = (w >> 2) * 128;
    const int wn = (w & 3) * 64;
    const int rA = w * 8 + (lane >> 3);
    const int cgs = (lane & 7) ^ (rA & 7);
    const u16* ap[4]; const u16* bp[4];
#pragma unroll
    for (int j = 0; j < 4; ++j) {
      long arow = (long)bx * 256 + rA + j * 64; if (arow > kNRoi - 1) arow = kNRoi - 1;
      ap[j] = A1 + arow * kKin + kb + cgs * 8;
      bp[j] = W1T + (long)(by * 256 + rA + j * 64) * kKin + kb + cgs * 8;
    }
#define STAGE1(b) do { _Pragma("unroll") for (int j_ = 0; j_ < 4; ++j_) { \
      GLDS(ap[j_], &As[b][w * 512 + j_ * 4096]); ap[j_] += 64; \
      GLDS(bp[j_], &Bs[b][w * 512 + j_ * 4096]); bp[j_] += 64; } } while (0)
    const int fr = lane & 15, q = lane >> 4;
    const int g0 = (q ^ (fr & 7)) * 8, g1 = ((4 + q) ^ (fr & 7)) * 8;
    f32x4 acc[8][4] = {};
    STAGE1(0);
    int cur = 0;
    for (int t = 0; t < NT; ++t) {
      const int nb = cur ^ 1;
      const bool more = (t + 1 < NT);
      __builtin_amdgcn_s_barrier();                   // buf[nb] free
      if (more) {
        STAGE1(nb);
        asm volatile("s_waitcnt vmcnt(8)" ::: "memory"); // tile t (iter-old) landed
      } else {
        asm volatile("s_waitcnt vmcnt(0)" ::: "memory");
      }
      __builtin_amdgcn_s_barrier();                   // tile t visible
      __builtin_amdgcn_sched_barrier(0);
      const u16* as_ = As[cur];
      const u16* bs_ = Bs[cur];
      bf16x8 a0[8], b0[4], a1[8], b1[4];
#pragma unroll
      for (int i = 0; i < 8; ++i) a0[i] = *(const bf16x8*)(as_ + (wm + i * 16 + fr) * 64 + g0);
#pragma unroll
      for (int i = 0; i < 4; ++i) b0[i] = *(const bf16x8*)(bs_ + (wn + i * 16 + fr) * 64 + g0);
      __builtin_amdgcn_s_setprio(1);
#pragma unroll
      for (int mi = 0; mi < 8; ++mi)
#pragma unroll
        for (int ni = 0; ni < 4; ++ni)
          acc[mi][ni] = __builtin_amdgcn_mfma_f32_16x16x32_bf16(a0[mi], b0[ni], acc[mi][ni], 0, 0, 0);
      __builtin_amdgcn_s_setprio(0);
#pragma unroll
      for (int i = 0; i < 8; ++i) a1[i] = *(const bf16x8*)(as_ + (wm + i * 16 + fr) * 64 + g1);
#pragma unroll
      for (int i = 0; i < 4; ++i) b1[i] = *(const bf16x8*)(bs_ + (wn + i * 16 + fr) * 64 + g1);
      __builtin_amdgcn_s_setprio(1);
#pragma unroll
      for (int mi = 0; mi < 8; ++mi)
#pragma unroll
        for (int ni = 0; ni < 4; ++ni)
          acc[mi][ni] = __builtin_amdgcn_mfma_f32_16x16x32_bf16(a1[mi], b1[ni], acc[mi][ni], 0, 0, 0);
      __builtin_amdgcn_s_setprio(0);
      cur = nb;
    }
#undef STAGE1
    const int row0 = bx * 256 + wm + q * 4;
    const int col0 = by * 256 + wn + fr;
#pragma unroll
    for (int mi = 0; mi < 8; ++mi)
#pragma unroll
      for (int ni = 0; ni < 4; ++ni)
#pragma unroll
        for (int e = 0; e < 4; ++e)
          atomicAdd(&X[(long)(row0 + mi * 16 + e) * kHid + col0 + ni * 16], acc[mi][ni][e]);
  }
  gsync();

  // ============ phase 2: BN1 column stats ============
  {
    const int col = g & 1023;
    const int r0 = (g >> 10) * 16;
    float s = 0.f, ss = 0.f;
    for (int r = r0; r < r0 + 16; ++r)
      if (r < kNRoi) { float x = X[(long)r * kHid + col]; s += x; ss += x * x; }
    atomicAdd(&S1[col], s); atomicAdd(&SS1[col], ss);
  }
  gsync();

  // ============ phase 3: BN1 + ReLU -> H ============
  bn_phase(X, S1, SS1, gamma1, beta1, H, g);
  gsync();

  // ============ phase 4: GEMM2 (direct-store, z=4) ============
  {
    const int z = bl & 3, tile = bl >> 2;
    gemm_bn128(H, W2T, Pz + (long)z * 2097152L, tile & 7, tile >> 3,
               z * 256, 4, kHid, As, Bs, tid);
  }
  gsync();

  // ============ phase 5: reduce partials -> X + BN2 stats ============
  {
    const int col = g & 1023;
    const int r0 = (g >> 10) * 16;
    float s = 0.f, ss = 0.f;
    for (int r = r0; r < r0 + 16; ++r) {
      float x = 0.f;
#pragma unroll
      for (int zz = 0; zz < 4; ++zz)
        x += Pz[(long)zz * 2097152L + (long)r * kHid + col];
      X[(long)r * kHid + col] = x;
      if (r < kNRoi) { s += x; ss += x * x; }
    }
    atomicAdd(&S2[col], s); atomicAdd(&SS2[col], ss);
  }
  gsync();

  // ============ phase 6: BN2 + ReLU -> H ============
  bn_phase(X, S2, SS2, gamma2, beta2, H, g);
  gsync();

  // ============ phase 7: GEMM3 (direct-store, z=8) ============
  {
    const int z = bl & 7, tile = bl >> 3;
    gemm_bn128(H, WHT, Pz + (long)z * 1048576L, tile & 7, tile >> 3,
               z * 128, 2, kNOutPad, As, Bs, tid);
  }
  gsync();

  // ============ phase 8: sum 8 partials + bias + softmax + outputs ============
  {
    const int row = bl * 8 + w;
    if (row < kNRoi) {
      const float* xr = Pz + (long)row * kNOutPad;
      float v0 = 0.f, v1 = 0.f;
#pragma unroll
      for (int z = 0; z < 8; ++z) v0 += xr[(long)z * 1048576L + lane];
      v0 += blg[lane];
      if (lane < kNC - 64) {
#pragma unroll
        for (int z = 0; z < 8; ++z) v1 += xr[(long)z * 1048576L + 64 + lane];
        v1 += blg[64 + lane];
      } else v1 = -3.0e38f;
      float m = fmaxf(v0, v1);
#pragma unroll
      for (int off = 32; off > 0; off >>= 1) m = fmaxf(m, __shfl_xor(m, off, 64));
      float e0 = __expf(v0 - m);
      float e1 = (lane < kNC - 64) ? __expf(v1 - m) : 0.f;
      float s = e0 + e1;
#pragma unroll
      for (int off = 32; off > 0; off >>= 1) s += __shfl_xor(s, off, 64);
      float inv = 1.f / s;
      float* lo = out + (long)row * kNC;
      float* pr = out + (long)kNRoi * kNC + (long)row * kNC;
      float* de = out + 2L * kNRoi * kNC + (long)row * kND;
      lo[lane] = v0;
      pr[lane] = e0 * inv;
      if (lane < kNC - 64) { lo[64 + lane] = v1; pr[64 + lane] = e1 * inv; }
#pragma unroll
      for (int j = 0; j < 5; ++j) {
        int c = lane + 64 * j;
        float d = 0.f;
#pragma unroll
        for (int z = 0; z < 8; ++z) d += xr[(long)z * 1048576L + kNC + c];
        de[c] = d + bdl[c];
      }
      if (lane < 4) {
        int c = lane + 320;
        float d = 0.f;
#pragma unroll
        for (int z = 0; z < 8; ++z) d += xr[(long)z * 1048576L + kNC + c];
        de[c] = d + bdl[c];
      }
    }
  }
}

// ---- launch ----------------------------------------------------------------
extern "C" void kernel_launch(void* const* d_in, const int* in_sizes, int n_in,
                              void* d_out, int out_size, void* d_ws, size_t ws_size,
                              hipStream_t stream) {
  (void)in_sizes; (void)n_in; (void)out_size; (void)ws_size;
  const float* pooled   = (const float*)d_in[0];
  const float* w1       = (const float*)d_in[1];
  const float* gamma1   = (const float*)d_in[3];
  const float* beta1    = (const float*)d_in[4];
  const float* w2       = (const float*)d_in[5];
  const float* gamma2   = (const float*)d_in[7];
  const float* beta2    = (const float*)d_in[8];
  const float* w_logits = (const float*)d_in[9];
  const float* b_logits = (const float*)d_in[10];
  const float* w_delta  = (const float*)d_in[11];
  const float* b_delta  = (const float*)d_in[12];

  char* ws = (char*)d_ws;
  // Layout (bytes), max end = 91,611,136 == proven-safe bound:
  u16*   W1T = (u16*)(ws + 0);            // [1024][12544] bf16  25,690,112
  u16*   W2T = (u16*)(ws + 25690112);     // [1024][1024]  bf16   2,097,152
  u16*   WHT = (u16*)(ws + 27787264);     // [512][1024]   bf16   1,048,576
  float* S   = (float*)(ws + 28835840);   // S1|SS1|S2|SS2        16,384
  u16*   H   = (u16*)(ws + 28852224);     // [2048][1024]  bf16   4,194,304
  float* X   = (float*)(ws + 33046528);   // [2048][1024]  f32    8,388,608
  u16*   A1  = (u16*)(ws + 41435136);     // [2000][12544] bf16  50,176,000 (dead after GEMM1)
  float* Pz  = (float*)(ws + 41435136);   // partials <=33,554,432, overlap dead A1

  mega<<<256, 512, 0, stream>>>(pooled, w1, w2, w_logits, w_delta,
                                gamma1, beta1, gamma2, beta2,
                                b_logits, b_delta,
                                A1, W1T, W2T, WHT, X, S, H, Pz, (float*)d_out);
}